// Round 3
// baseline (8595.789 us; speedup 1.0000x reference)
//
#include <hip/hip_runtime.h>
#include <hip/hip_bf16.h>

#define S 2048
#define HD 512
#define EDIM 512
#define NT 12
#define G4 2048            // 4*HD gate rows
#define NWGD 64            // workgroups per direction
#define JPW 8              // hidden units per WG

typedef unsigned short ushort_t;
typedef unsigned int uint_t;

__device__ __forceinline__ ushort_t f2b(float f) {
    uint_t u = __float_as_uint(f);
    uint_t r = u + 0x7fffu + ((u >> 16) & 1u);
    return (ushort_t)(r >> 16);
}
__device__ __forceinline__ float b2f(ushort_t h) {
    return __uint_as_float(((uint_t)h) << 16);
}
__device__ __forceinline__ float sigm(float x) { return 1.f / (1.f + __expf(-x)); }
__device__ __forceinline__ float tanh_(float x) {
    float e = __expf(2.f * x);
    return 1.f - 2.f / (e + 1.f);
}

// ---------------- xw GEMM: xwT[d][r][t] = emb[tok(d,t)] . wih_d[r] + b_d[r] (TRANSPOSED out) ----
__global__ __launch_bounds__(256, 2)
void xw_gemm(const int* __restrict__ sentence, const float* __restrict__ emb,
             const float* __restrict__ wih_f, const float* __restrict__ b_f,
             const float* __restrict__ wih_b, const float* __restrict__ b_b,
             ushort_t* __restrict__ xwT) {
    __shared__ float As[32][68];
    __shared__ float Bs[32][68];
    __shared__ int toks[64];
    const int tid = threadIdx.x;
    const int tbase = blockIdx.x * 64;
    const int rbase = blockIdx.y * 64;
    const int dir = blockIdx.z;
    const float* wih = dir ? wih_b : wih_f;
    const float* bia = dir ? b_b : b_f;
    if (tid < 64) {
        int tt = tbase + tid;
        toks[tid] = sentence[dir ? (S - 1 - tt) : tt];
    }
    __syncthreads();
    const int lm = tid >> 2;
    const int lk = (tid & 3) * 8;
    const int ty = tid >> 4, tx = tid & 15;
    const float* aBase = emb + (size_t)toks[lm] * EDIM + lk;
    const float* bBase = wih + (size_t)(rbase + lm) * EDIM + lk;
    float acc[4][4];
#pragma unroll
    for (int i = 0; i < 4; ++i)
#pragma unroll
        for (int j = 0; j < 4; ++j) acc[i][j] = 0.f;

    for (int kcc = 0; kcc < EDIM; kcc += 32) {
        float4 a0 = ((const float4*)(aBase + kcc))[0];
        float4 a1 = ((const float4*)(aBase + kcc))[1];
        float4 b0 = ((const float4*)(bBase + kcc))[0];
        float4 b1 = ((const float4*)(bBase + kcc))[1];
        __syncthreads();
        As[lk + 0][lm] = a0.x; As[lk + 1][lm] = a0.y; As[lk + 2][lm] = a0.z; As[lk + 3][lm] = a0.w;
        As[lk + 4][lm] = a1.x; As[lk + 5][lm] = a1.y; As[lk + 6][lm] = a1.z; As[lk + 7][lm] = a1.w;
        Bs[lk + 0][lm] = b0.x; Bs[lk + 1][lm] = b0.y; Bs[lk + 2][lm] = b0.z; Bs[lk + 3][lm] = b0.w;
        Bs[lk + 4][lm] = b1.x; Bs[lk + 5][lm] = b1.y; Bs[lk + 6][lm] = b1.z; Bs[lk + 7][lm] = b1.w;
        __syncthreads();
#pragma unroll
        for (int kk = 0; kk < 32; ++kk) {
            float4 a4 = *(const float4*)&As[kk][ty * 4];
            float4 b4 = *(const float4*)&Bs[kk][tx * 4];
            float av[4] = {a4.x, a4.y, a4.z, a4.w};
            float bv[4] = {b4.x, b4.y, b4.z, b4.w};
#pragma unroll
            for (int i = 0; i < 4; ++i)
#pragma unroll
                for (int j = 0; j < 4; ++j) acc[i][j] = fmaf(av[i], bv[j], acc[i][j]);
        }
    }
    float4 bi = *(const float4*)&bia[rbase + tx * 4];
    float bvv[4] = {bi.x, bi.y, bi.z, bi.w};
    // transposed epilogue: row-major [row][t]
#pragma unroll
    for (int j = 0; j < 4; ++j) {
        ushort4 o;
        o.x = f2b(acc[0][j] + bvv[j]);
        o.y = f2b(acc[1][j] + bvv[j]);
        o.z = f2b(acc[2][j] + bvv[j]);
        o.w = f2b(acc[3][j] + bvv[j]);
        ushort_t* p = xwT + ((size_t)dir * G4 + rbase + tx * 4 + j) * S + tbase + ty * 4;
        *(ushort4*)p = o;
    }
}

// ---------------- LSTM recurrence: 128 WGs, barrier-free waves, reg-stationary weights ------
// Wave-lane layout: lw = kc(3b) | gate(2b) | jl(1b). Each lane: 1 gate row x 64 k in VGPRs.
// Each wave keeps a PRIVATE padded h copy in LDS (polls all 512 itself) -> no __syncthreads.
__global__ __launch_bounds__(256, 1)
void lstm_rec(const float* __restrict__ whh_f, const float* __restrict__ whh_b,
              const float* __restrict__ h0, const float* __restrict__ c0,
              const ushort_t* __restrict__ xwT, float* hs) {
    __shared__ float hstage[4 * 544];           // 4 waves x 8 chunks x 68 dwords (pad -> no conflicts)
    __shared__ ushort_t xstage[4][2][512];      // 4 waves x dbuf x (8 rows x 64 t)
    const int tid = threadIdx.x;
    const int wv = tid >> 6;
    const int lw = tid & 63;
    const int dir = blockIdx.x >> 6;
    const int wg = blockIdx.x & 63;
    const int jbase = wg * JPW;
    const int kc = lw & 7;
    const int gate = (lw >> 3) & 3;
    const int jl = lw >> 5;
    const int jglob = jbase + wv * 2 + jl;
    const int row = gate * HD + jglob;
    const float* whh = dir ? whh_b : whh_f;

    // register-stationary weights: 64 f32 (16 float4)
    float4 w[16];
#pragma unroll
    for (int i = 0; i < 16; ++i)
        w[i] = *(const float4*)&whh[(size_t)row * HD + kc * 64 + i * 4];

    const ushort_t* xwd = xwT + (size_t)dir * G4 * S;
    float* hsd = hs + (size_t)dir * S * HD;

    // xw staging: run ri = g*2 + j2  -> row g*HD + jbase + wv*2 + j2 ; 8 lanes x 16B per run
    const int ri = lw >> 3;
    const ushort_t* sbase = xwd + (size_t)((ri >> 1) * HD + jbase + wv * 2 + (ri & 1)) * S;
    {   // preload chunk 0
        uint4 vch = *(const uint4*)(sbase + (lw & 7) * 8);
        *(uint4*)&xstage[wv][0][ri * 64 + (lw & 7) * 8] = vch;
    }

    const bool upd = (lw & 31) == 0;
    float cj = upd ? c0[dir * HD + jglob] : 0.f;

    // stage h0 into this wave's private copy (8 floats/lane)
    {
        float4 a = *(const float4*)&h0[dir * HD + lw * 8];
        float4 b4 = *(const float4*)&h0[dir * HD + lw * 8 + 4];
        float* d = &hstage[wv * 544 + (lw >> 3) * 68 + (lw & 7) * 8];
        *(float4*)d = a;
        *(float4*)(d + 4) = b4;
    }

    const float* hb = &hstage[wv * 544 + kc * 68];
    for (int t = 0; t < S; ++t) {
        if ((t & 63) == 0 && t + 64 < S) {       // prefetch next xw chunk (wave-uniform)
            uint4 vch = *(const uint4*)(sbase + (t + 64) + (lw & 7) * 8);
            *(uint4*)&xstage[wv][((t >> 6) + 1) & 1][ri * 64 + (lw & 7) * 8] = vch;
        }
        // matvec: this lane's row x its 64-k chunk
        float4 a4 = {0.f, 0.f, 0.f, 0.f};
#pragma unroll
        for (int i = 0; i < 16; ++i) {
            float4 h4 = *(const float4*)&hb[i * 4];
            a4.x = fmaf(w[i].x, h4.x, a4.x);
            a4.y = fmaf(w[i].y, h4.y, a4.y);
            a4.z = fmaf(w[i].z, h4.z, a4.z);
            a4.w = fmaf(w[i].w, h4.w, a4.w);
        }
        float acc = (a4.x + a4.y) + (a4.z + a4.w);
        acc += __shfl_xor(acc, 1);
        acc += __shfl_xor(acc, 2);
        acc += __shfl_xor(acc, 4);
        const int gb = lw & 32;
        float g0 = __shfl(acc, gb);
        float g1 = __shfl(acc, gb + 8);
        float g2 = __shfl(acc, gb + 16);
        float g3 = __shfl(acc, gb + 24);
        if (upd) {
            const ushort_t* xs = &xstage[wv][(t >> 6) & 1][jl * 64 + (t & 63)];
            float gi = g0 + b2f(xs[0]);
            float gf = g1 + b2f(xs[128]);
            float gg = g2 + b2f(xs[256]);
            float go = g3 + b2f(xs[384]);
            float ii = sigm(gi), ff = sigm(gf), gv = tanh_(gg), oo = sigm(go);
            cj = ff * cj + ii * gv;
            float hnew = oo * tanh_(cj);
            __hip_atomic_store(&hsd[(size_t)t * HD + jglob], hnew,
                               __ATOMIC_RELAXED, __HIP_MEMORY_SCOPE_AGENT);
        }
        if (t < S - 1) {
            // poll all 512 h[t]: lane covers u64 slots lw + 64q (floats 2lw+128q)
            const unsigned long long* pb = (const unsigned long long*)&hsd[(size_t)t * HD];
            unsigned long long v[4];
            unsigned msk = 0;
            do {
#pragma unroll
                for (int q = 0; q < 4; ++q)
                    if (!(msk & (1u << q))) {
                        unsigned long long x = __hip_atomic_load(
                            pb + lw + 64 * q, __ATOMIC_RELAXED, __HIP_MEMORY_SCOPE_AGENT);
                        if ((uint_t)x != 0xFFFFFFFFu && (uint_t)(x >> 32) != 0xFFFFFFFFu) {
                            v[q] = x;
                            msk |= 1u << q;
                        }
                    }
            } while (msk != 15u);
#pragma unroll
            for (int q = 0; q < 4; ++q) {
                int p = 2 * lw + 128 * q;
                *(unsigned long long*)&hstage[wv * 544 + (p >> 6) * 68 + (p & 63)] = v[q];
            }
        }
    }
}

// ---------------- feats: [S][12] = concat(hf, hb_rev) @ w_out.T + b_out ----------------
__global__ __launch_bounds__(256)
void feats_k(const float* __restrict__ hs, const float* __restrict__ w_out,
             const float* __restrict__ b_out, float* __restrict__ feats) {
    const int t = blockIdx.x, tid = threadIdx.x;
    float4 h4;
    if (tid < 128)
        h4 = *(const float4*)&hs[(size_t)t * HD + tid * 4];
    else
        h4 = *(const float4*)&hs[(size_t)S * HD + (size_t)(S - 1 - t) * HD + (tid - 128) * 4];
    float acc[NT];
#pragma unroll
    for (int tg = 0; tg < NT; ++tg) {
        float4 w4 = *(const float4*)&w_out[(size_t)tg * 1024 + tid * 4];
        acc[tg] = h4.x * w4.x + h4.y * w4.y + h4.z * w4.z + h4.w * w4.w;
    }
#pragma unroll
    for (int m = 1; m < 64; m <<= 1)
#pragma unroll
        for (int tg = 0; tg < NT; ++tg) acc[tg] += __shfl_xor(acc[tg], m);
    __shared__ float part[4][NT];
    if ((tid & 63) == 0) {
#pragma unroll
        for (int tg = 0; tg < NT; ++tg) part[tid >> 6][tg] = acc[tg];
    }
    __syncthreads();
    if (tid < NT)
        feats[(size_t)t * NT + tid] =
            part[0][tid] + part[1][tid] + part[2][tid] + part[3][tid] + b_out[tid];
}

// ---------------- CRF: forward algorithm + gold score, single block ----------------
__global__ __launch_bounds__(256, 1)
void crf_k(const float* __restrict__ feats, const int* __restrict__ gold,
           const float* __restrict__ trans, float* __restrict__ out) {
    extern __shared__ float sfeats[];      // S*NT floats = 96KB
    __shared__ float red[256];
    __shared__ float nprev[NT];
    __shared__ float tr[144];
    __shared__ float gold_sh;
    const int tid = threadIdx.x;
    for (int i = tid; i < S * NT / 4; i += 256)
        ((float4*)sfeats)[i] = ((const float4*)feats)[i];
    if (tid < 144) tr[tid] = trans[tid];
    __syncthreads();
    // gold score
    float gsum = 0.f;
    for (int t = tid; t < S; t += 256) {
        int a = gold[t];
        int b = t ? gold[t - 1] : 0;
        gsum += tr[a * NT + b] + sfeats[t * NT + a];
    }
    red[tid] = gsum;
    __syncthreads();
    for (int s = 128; s; s >>= 1) {
        if (tid < s) red[tid] += red[tid + s];
        __syncthreads();
    }
    if (tid == 0) gold_sh = red[0] + tr[1 * NT + gold[S - 1]];
    __syncthreads();
    // forward algorithm: i = tid/16 (next tag), j = tid%16 (prev tag)
    const int i = tid >> 4, j = tid & 15;
    const bool act = (tid < 192) && (j < NT);
    float tij = act ? tr[i * NT + j] : -3e38f;
    float prev = (j == 0) ? 0.f : -1e6f;
    for (int t = 0; t < S; ++t) {
        float v = act ? (prev + tij) : -3e38f;
        float mx = v;
        mx = fmaxf(mx, __shfl_xor(mx, 1));
        mx = fmaxf(mx, __shfl_xor(mx, 2));
        mx = fmaxf(mx, __shfl_xor(mx, 4));
        mx = fmaxf(mx, __shfl_xor(mx, 8));
        float e = __expf(v - mx);
        float ss = e;
        ss += __shfl_xor(ss, 1);
        ss += __shfl_xor(ss, 2);
        ss += __shfl_xor(ss, 4);
        ss += __shfl_xor(ss, 8);
        if (tid < 192 && j == 0) nprev[i] = mx + __logf(ss) + sfeats[t * NT + i];
        __syncthreads();
        prev = nprev[j < NT ? j : 0];
        __syncthreads();
    }
    if (tid < 64) {
        float v2 = (tid < NT) ? prev + tr[1 * NT + tid] : -3e38f;
        float mx = v2;
        mx = fmaxf(mx, __shfl_xor(mx, 1));
        mx = fmaxf(mx, __shfl_xor(mx, 2));
        mx = fmaxf(mx, __shfl_xor(mx, 4));
        mx = fmaxf(mx, __shfl_xor(mx, 8));
        float e = __expf(v2 - mx);
        float ss = e;
        ss += __shfl_xor(ss, 1);
        ss += __shfl_xor(ss, 2);
        ss += __shfl_xor(ss, 4);
        ss += __shfl_xor(ss, 8);
        if (tid == 0) out[0] = (mx + __logf(ss)) - gold_sh;
    }
}

extern "C" void kernel_launch(void* const* d_in, const int* in_sizes, int n_in,
                              void* d_out, int out_size, void* d_ws, size_t ws_size,
                              hipStream_t stream) {
    const int* sentence = (const int*)d_in[0];
    const int* gold = (const int*)d_in[1];
    const float* emb = (const float*)d_in[2];
    const float* wih_f = (const float*)d_in[3];
    const float* whh_f = (const float*)d_in[4];
    const float* b_f = (const float*)d_in[5];
    const float* wih_b = (const float*)d_in[6];
    const float* whh_b = (const float*)d_in[7];
    const float* b_b = (const float*)d_in[8];
    const float* w_out = (const float*)d_in[9];
    const float* b_out = (const float*)d_in[10];
    const float* trans = (const float*)d_in[11];
    const float* h0 = (const float*)d_in[12];
    const float* c0 = (const float*)d_in[13];
    float* out = (float*)d_out;

    char* ws = (char*)d_ws;
    const size_t XW_B = (size_t)2 * S * G4 * 2;          // 16,777,216
    const size_t HS_B = (size_t)2 * S * HD * 4;          // 8,388,608
    ushort_t* xwT = (ushort_t*)ws;
    float* hs = (float*)(ws + XW_B);
    float* feats = (float*)(ws + XW_B + HS_B);

    // canary-fill h state buffer (0xFFFFFFFF, impossible output value)
    hipMemsetAsync(hs, 0xFF, HS_B, stream);

    dim3 gg(S / 64, G4 / 64, 2);
    xw_gemm<<<gg, 256, 0, stream>>>(sentence, emb, wih_f, b_f, wih_b, b_b, xwT);

    lstm_rec<<<2 * NWGD, 256, 0, stream>>>(whh_f, whh_b, h0, c0, xwT, hs);

    feats_k<<<S, 256, 0, stream>>>(hs, w_out, b_out, feats);

    const size_t CRF_LDS = (size_t)S * NT * 4;           // 98,304 B
    hipFuncSetAttribute((const void*)crf_k,
                        hipFuncAttributeMaxDynamicSharedMemorySize, (int)CRF_LDS);
    crf_k<<<1, 256, CRF_LDS, stream>>>(feats, gold, trans, out);
}

// Round 4
// 6613.189 us; speedup vs baseline: 1.2998x; 1.2998x over previous
//
#include <hip/hip_runtime.h>
#include <hip/hip_bf16.h>

#define S 2048
#define HD 512
#define EDIM 512
#define NT 12
#define G4 2048            // 4*HD gate rows
#define NWGD 64            // workgroups per direction
#define JPW 8              // hidden units per WG

typedef unsigned short ushort_t;
typedef unsigned int uint_t;

__device__ __forceinline__ ushort_t f2b(float f) {
    uint_t u = __float_as_uint(f);
    uint_t r = u + 0x7fffu + ((u >> 16) & 1u);
    return (ushort_t)(r >> 16);
}
__device__ __forceinline__ float b2f(ushort_t h) {
    return __uint_as_float(((uint_t)h) << 16);
}
__device__ __forceinline__ float sigm(float x) { return 1.f / (1.f + __expf(-x)); }
__device__ __forceinline__ float tanh_(float x) {
    float e = __expf(2.f * x);
    return 1.f - 2.f / (e + 1.f);
}

// ---------------- xw GEMM: xwT[d][r][t] = emb[tok(d,t)] . wih_d[r] + b_d[r] (TRANSPOSED out) ----
__global__ __launch_bounds__(256, 2)
void xw_gemm(const int* __restrict__ sentence, const float* __restrict__ emb,
             const float* __restrict__ wih_f, const float* __restrict__ b_f,
             const float* __restrict__ wih_b, const float* __restrict__ b_b,
             ushort_t* __restrict__ xwT) {
    __shared__ float As[32][68];
    __shared__ float Bs[32][68];
    __shared__ int toks[64];
    const int tid = threadIdx.x;
    const int tbase = blockIdx.x * 64;
    const int rbase = blockIdx.y * 64;
    const int dir = blockIdx.z;
    const float* wih = dir ? wih_b : wih_f;
    const float* bia = dir ? b_b : b_f;
    if (tid < 64) {
        int tt = tbase + tid;
        toks[tid] = sentence[dir ? (S - 1 - tt) : tt];
    }
    __syncthreads();
    const int lm = tid >> 2;
    const int lk = (tid & 3) * 8;
    const int ty = tid >> 4, tx = tid & 15;
    const float* aBase = emb + (size_t)toks[lm] * EDIM + lk;
    const float* bBase = wih + (size_t)(rbase + lm) * EDIM + lk;
    float acc[4][4];
#pragma unroll
    for (int i = 0; i < 4; ++i)
#pragma unroll
        for (int j = 0; j < 4; ++j) acc[i][j] = 0.f;

    for (int kcc = 0; kcc < EDIM; kcc += 32) {
        float4 a0 = ((const float4*)(aBase + kcc))[0];
        float4 a1 = ((const float4*)(aBase + kcc))[1];
        float4 b0 = ((const float4*)(bBase + kcc))[0];
        float4 b1 = ((const float4*)(bBase + kcc))[1];
        __syncthreads();
        As[lk + 0][lm] = a0.x; As[lk + 1][lm] = a0.y; As[lk + 2][lm] = a0.z; As[lk + 3][lm] = a0.w;
        As[lk + 4][lm] = a1.x; As[lk + 5][lm] = a1.y; As[lk + 6][lm] = a1.z; As[lk + 7][lm] = a1.w;
        Bs[lk + 0][lm] = b0.x; Bs[lk + 1][lm] = b0.y; Bs[lk + 2][lm] = b0.z; Bs[lk + 3][lm] = b0.w;
        Bs[lk + 4][lm] = b1.x; Bs[lk + 5][lm] = b1.y; Bs[lk + 6][lm] = b1.z; Bs[lk + 7][lm] = b1.w;
        __syncthreads();
#pragma unroll
        for (int kk = 0; kk < 32; ++kk) {
            float4 a4 = *(const float4*)&As[kk][ty * 4];
            float4 b4 = *(const float4*)&Bs[kk][tx * 4];
            float av[4] = {a4.x, a4.y, a4.z, a4.w};
            float bv[4] = {b4.x, b4.y, b4.z, b4.w};
#pragma unroll
            for (int i = 0; i < 4; ++i)
#pragma unroll
                for (int j = 0; j < 4; ++j) acc[i][j] = fmaf(av[i], bv[j], acc[i][j]);
        }
    }
    float4 bi = *(const float4*)&bia[rbase + tx * 4];
    float bvv[4] = {bi.x, bi.y, bi.z, bi.w};
    // transposed epilogue: row-major [row][t]
#pragma unroll
    for (int j = 0; j < 4; ++j) {
        ushort4 o;
        o.x = f2b(acc[0][j] + bvv[j]);
        o.y = f2b(acc[1][j] + bvv[j]);
        o.z = f2b(acc[2][j] + bvv[j]);
        o.w = f2b(acc[3][j] + bvv[j]);
        ushort_t* p = xwT + ((size_t)dir * G4 + rbase + tx * 4 + j) * S + tbase + ty * 4;
        *(ushort4*)p = o;
    }
}

// ---------------- LSTM recurrence: flag-published steps, shared hstage, 2 barriers/step ----
// Wave-lane layout: lw = jl(1b) | gate(2b) | kc(3b). Wave wv owns units jbase+wv*2+{0,1}.
// Publish: upd lanes atomic-store h (write-through LLC); __syncthreads vmcnt(0) drain acts as
// release; tid0 stores flag[wg]=t+1. Consume: wave wv polls 16 flags of its h-quarter (64B),
// one-shot bulk read 512B, ds_write to shared hstage, barrier.
__global__ __launch_bounds__(256, 1)
void lstm_rec(const float* __restrict__ whh_f, const float* __restrict__ whh_b,
              const float* __restrict__ h0, const float* __restrict__ c0,
              const ushort_t* __restrict__ xwT, float* hs, int* flags) {
    __shared__ float hstage[544];               // 8 chunks x 68 dwords (pad -> conflict-free)
    __shared__ ushort_t xstage[4][2][512];      // per-wave dbuf xw chunk (8 rows x 64 t)
    const int tid = threadIdx.x;
    const int wv = tid >> 6;
    const int lw = tid & 63;
    const int dir = blockIdx.x >> 6;
    const int wg = blockIdx.x & 63;
    const int jbase = wg * JPW;
    const int kc = lw & 7;
    const int gate = (lw >> 3) & 3;
    const int jl = lw >> 5;
    const int j0 = jbase + wv * 2;
    const int row = gate * HD + j0 + jl;
    const float* whh = dir ? whh_b : whh_f;

    // register-stationary weights: 64 f32 (16 float4) per lane
    float4 w[16];
#pragma unroll
    for (int i = 0; i < 16; ++i)
        w[i] = *(const float4*)&whh[(size_t)row * HD + kc * 64 + i * 4];

    const ushort_t* xwd = xwT + (size_t)dir * G4 * S;
    float* hsd = hs + (size_t)dir * S * HD;
    int* flg = flags + dir * 256;               // 64 producers x 4-dword stride

    // xw staging: run ri = g*2 + j2 -> row g*HD + j0 + j2
    const int ri = lw >> 3;
    const ushort_t* sbase = xwd + (size_t)((ri >> 1) * HD + j0 + (ri & 1)) * S;
    {
        uint4 v0 = *(const uint4*)(sbase + (lw & 7) * 8);
        *(uint4*)&xstage[wv][0][ri * 64 + (lw & 7) * 8] = v0;
    }

    const bool upd = (lw & 31) == 0;
    float cj = upd ? c0[dir * HD + j0 + jl] : 0.f;

    // stage h0: each wave writes the FULL copy (redundant same-value -> benign)
    {
        int p = lw * 8;
        float4 a = *(const float4*)&h0[dir * HD + p];
        float4 b4 = *(const float4*)&h0[dir * HD + p + 4];
        float* d = &hstage[(p >> 6) * 68 + (p & 63)];
        *(float4*)d = a;
        *(float4*)(d + 4) = b4;
    }

    const float* hb = &hstage[kc * 68];
    const int gb = lw & 32;
    for (int t = 0; t < S; ++t) {
        if ((t & 63) == 0 && t + 64 < S) {       // prefetch next xw chunk
            uint4 vch = *(const uint4*)(sbase + (t + 64) + (lw & 7) * 8);
            *(uint4*)&xstage[wv][((t >> 6) + 1) & 1][ri * 64 + (lw & 7) * 8] = vch;
        }
        // matvec: this lane's gate row x its 64-k chunk
        float4 a4 = {0.f, 0.f, 0.f, 0.f};
#pragma unroll
        for (int i = 0; i < 16; ++i) {
            float4 h4 = *(const float4*)&hb[i * 4];
            a4.x = fmaf(w[i].x, h4.x, a4.x);
            a4.y = fmaf(w[i].y, h4.y, a4.y);
            a4.z = fmaf(w[i].z, h4.z, a4.z);
            a4.w = fmaf(w[i].w, h4.w, a4.w);
        }
        float acc = (a4.x + a4.y) + (a4.z + a4.w);
        acc += __shfl_xor(acc, 1);
        acc += __shfl_xor(acc, 2);
        acc += __shfl_xor(acc, 4);
        float g0 = __shfl(acc, gb);
        float g1 = __shfl(acc, gb + 8);
        float g2 = __shfl(acc, gb + 16);
        float g3 = __shfl(acc, gb + 24);
        if (upd) {
            const ushort_t* xs = &xstage[wv][(t >> 6) & 1][jl * 64 + (t & 63)];
            float gi = g0 + b2f(xs[0]);
            float gf = g1 + b2f(xs[128]);
            float gg = g2 + b2f(xs[256]);
            float go = g3 + b2f(xs[384]);
            float ii = sigm(gi), ff = sigm(gf), gv = tanh_(gg), oo = sigm(go);
            cj = ff * cj + ii * gv;
            float hnew = oo * tanh_(cj);
            __hip_atomic_store(&hsd[(size_t)t * HD + j0 + jl], hnew,
                               __ATOMIC_RELAXED, __HIP_MEMORY_SCOPE_AGENT);
        }
        __syncthreads();                         // vmcnt(0) drain = release for all 4 waves
        if (tid == 0)
            __hip_atomic_store(&flg[wg * 4], t + 1, __ATOMIC_RELAXED,
                               __HIP_MEMORY_SCOPE_AGENT);
        if (t < S - 1) {
            // wave wv needs h quarter [wv*128, wv*128+128) = producers wv*16 .. wv*16+15
            int* fp = &flg[(wv * 16 + (lw & 15)) * 4];
            while (__hip_atomic_load(fp, __ATOMIC_RELAXED, __HIP_MEMORY_SCOPE_AGENT) <= t) {}
            unsigned long long v = __hip_atomic_load(
                (const unsigned long long*)&hsd[(size_t)t * HD] + wv * 64 + lw,
                __ATOMIC_RELAXED, __HIP_MEMORY_SCOPE_AGENT);
            int p = wv * 128 + 2 * lw;
            *(unsigned long long*)&hstage[(p >> 6) * 68 + (p & 63)] = v;
            __syncthreads();                     // merge quarters
        }
    }
}

// ---------------- feats: [S][12] = concat(hf, hb_rev) @ w_out.T + b_out ----------------
__global__ __launch_bounds__(256)
void feats_k(const float* __restrict__ hs, const float* __restrict__ w_out,
             const float* __restrict__ b_out, float* __restrict__ feats) {
    const int t = blockIdx.x, tid = threadIdx.x;
    float4 h4;
    if (tid < 128)
        h4 = *(const float4*)&hs[(size_t)t * HD + tid * 4];
    else
        h4 = *(const float4*)&hs[(size_t)S * HD + (size_t)(S - 1 - t) * HD + (tid - 128) * 4];
    float acc[NT];
#pragma unroll
    for (int tg = 0; tg < NT; ++tg) {
        float4 w4 = *(const float4*)&w_out[(size_t)tg * 1024 + tid * 4];
        acc[tg] = h4.x * w4.x + h4.y * w4.y + h4.z * w4.z + h4.w * w4.w;
    }
#pragma unroll
    for (int m = 1; m < 64; m <<= 1)
#pragma unroll
        for (int tg = 0; tg < NT; ++tg) acc[tg] += __shfl_xor(acc[tg], m);
    __shared__ float part[4][NT];
    if ((tid & 63) == 0) {
#pragma unroll
        for (int tg = 0; tg < NT; ++tg) part[tid >> 6][tg] = acc[tg];
    }
    __syncthreads();
    if (tid < NT)
        feats[(size_t)t * NT + tid] =
            part[0][tid] + part[1][tid] + part[2][tid] + part[3][tid] + b_out[tid];
}

// ---------------- CRF: forward algorithm + gold score, single block ----------------
__global__ __launch_bounds__(256, 1)
void crf_k(const float* __restrict__ feats, const int* __restrict__ gold,
           const float* __restrict__ trans, float* __restrict__ out) {
    extern __shared__ float sfeats[];      // S*NT floats = 96KB
    __shared__ float red[256];
    __shared__ float nprev[NT];
    __shared__ float tr[144];
    __shared__ float gold_sh;
    const int tid = threadIdx.x;
    for (int i = tid; i < S * NT / 4; i += 256)
        ((float4*)sfeats)[i] = ((const float4*)feats)[i];
    if (tid < 144) tr[tid] = trans[tid];
    __syncthreads();
    // gold score
    float gsum = 0.f;
    for (int t = tid; t < S; t += 256) {
        int a = gold[t];
        int b = t ? gold[t - 1] : 0;
        gsum += tr[a * NT + b] + sfeats[t * NT + a];
    }
    red[tid] = gsum;
    __syncthreads();
    for (int s = 128; s; s >>= 1) {
        if (tid < s) red[tid] += red[tid + s];
        __syncthreads();
    }
    if (tid == 0) gold_sh = red[0] + tr[1 * NT + gold[S - 1]];
    __syncthreads();
    // forward algorithm: i = tid/16 (next tag), j = tid%16 (prev tag)
    const int i = tid >> 4, j = tid & 15;
    const bool act = (tid < 192) && (j < NT);
    float tij = act ? tr[i * NT + j] : -3e38f;
    float prev = (j == 0) ? 0.f : -1e6f;
    for (int t = 0; t < S; ++t) {
        float v = act ? (prev + tij) : -3e38f;
        float mx = v;
        mx = fmaxf(mx, __shfl_xor(mx, 1));
        mx = fmaxf(mx, __shfl_xor(mx, 2));
        mx = fmaxf(mx, __shfl_xor(mx, 4));
        mx = fmaxf(mx, __shfl_xor(mx, 8));
        float e = __expf(v - mx);
        float ss = e;
        ss += __shfl_xor(ss, 1);
        ss += __shfl_xor(ss, 2);
        ss += __shfl_xor(ss, 4);
        ss += __shfl_xor(ss, 8);
        if (tid < 192 && j == 0) nprev[i] = mx + __logf(ss) + sfeats[t * NT + i];
        __syncthreads();
        prev = nprev[j < NT ? j : 0];
        __syncthreads();
    }
    if (tid < 64) {
        float v2 = (tid < NT) ? prev + tr[1 * NT + tid] : -3e38f;
        float mx = v2;
        mx = fmaxf(mx, __shfl_xor(mx, 1));
        mx = fmaxf(mx, __shfl_xor(mx, 2));
        mx = fmaxf(mx, __shfl_xor(mx, 4));
        mx = fmaxf(mx, __shfl_xor(mx, 8));
        float e = __expf(v2 - mx);
        float ss = e;
        ss += __shfl_xor(ss, 1);
        ss += __shfl_xor(ss, 2);
        ss += __shfl_xor(ss, 4);
        ss += __shfl_xor(ss, 8);
        if (tid == 0) out[0] = (mx + __logf(ss)) - gold_sh;
    }
}

extern "C" void kernel_launch(void* const* d_in, const int* in_sizes, int n_in,
                              void* d_out, int out_size, void* d_ws, size_t ws_size,
                              hipStream_t stream) {
    const int* sentence = (const int*)d_in[0];
    const int* gold = (const int*)d_in[1];
    const float* emb = (const float*)d_in[2];
    const float* wih_f = (const float*)d_in[3];
    const float* whh_f = (const float*)d_in[4];
    const float* b_f = (const float*)d_in[5];
    const float* wih_b = (const float*)d_in[6];
    const float* whh_b = (const float*)d_in[7];
    const float* b_b = (const float*)d_in[8];
    const float* w_out = (const float*)d_in[9];
    const float* b_out = (const float*)d_in[10];
    const float* trans = (const float*)d_in[11];
    const float* h0 = (const float*)d_in[12];
    const float* c0 = (const float*)d_in[13];
    float* out = (float*)d_out;

    char* ws = (char*)d_ws;
    const size_t XW_B = (size_t)2 * S * G4 * 2;          // 16,777,216
    const size_t HS_B = (size_t)2 * S * HD * 4;          // 8,388,608
    const size_t FT_B = (size_t)S * NT * 4;              // 98,304
    ushort_t* xwT = (ushort_t*)ws;
    float* hs = (float*)(ws + XW_B);
    float* feats = (float*)(ws + XW_B + HS_B);
    int* flags = (int*)(ws + XW_B + HS_B + FT_B);        // 2 dirs x 64 x 16B = 2 KB

    hipMemsetAsync(flags, 0, 2048, stream);

    dim3 gg(S / 64, G4 / 64, 2);
    xw_gemm<<<gg, 256, 0, stream>>>(sentence, emb, wih_f, b_f, wih_b, b_b, xwT);

    lstm_rec<<<2 * NWGD, 256, 0, stream>>>(whh_f, whh_b, h0, c0, xwT, hs, flags);

    feats_k<<<S, 256, 0, stream>>>(hs, w_out, b_out, feats);

    const size_t CRF_LDS = (size_t)S * NT * 4;           // 98,304 B
    hipFuncSetAttribute((const void*)crf_k,
                        hipFuncAttributeMaxDynamicSharedMemorySize, (int)CRF_LDS);
    crf_k<<<1, 256, CRF_LDS, stream>>>(feats, gold, trans, out);
}